// Round 1
// baseline (94.823 us; speedup 1.0000x reference)
//
#include <hip/hip_runtime.h>
#include <math.h>

#define NN 8192
#define NEMBD 128
#define NHID 64
#define NCLS 16
#define MAXN 256
#define NEG_SLOPE 0.2f

__device__ __forceinline__ float wave_max64(float v) {
    v = fmaxf(v, __shfl_xor(v, 1));
    v = fmaxf(v, __shfl_xor(v, 2));
    v = fmaxf(v, __shfl_xor(v, 4));
    v = fmaxf(v, __shfl_xor(v, 8));
    v = fmaxf(v, __shfl_xor(v, 16));
    v = fmaxf(v, __shfl_xor(v, 32));
    return v;
}
__device__ __forceinline__ float wave_sum64(float v) {
    v += __shfl_xor(v, 1);
    v += __shfl_xor(v, 2);
    v += __shfl_xor(v, 4);
    v += __shfl_xor(v, 8);
    v += __shfl_xor(v, 16);
    v += __shfl_xor(v, 32);
    return v;
}

// h1[i][f] = sum_k x[i][k]*W1[k][f];  als[i]=h1[i].a1s; ald[i]=h1[i].a1d
// wave per row, lane = feature (NHID==64)
__global__ __launch_bounds__(256) void k_h1(
    const float* __restrict__ x, const float* __restrict__ W1,
    const float* __restrict__ a1s, const float* __restrict__ a1d,
    float* __restrict__ h1, float* __restrict__ als, float* __restrict__ ald) {
    int wid = threadIdx.x >> 6, lane = threadIdx.x & 63;
    int row = blockIdx.x * 4 + wid;
    const float* xr = x + (size_t)row * NEMBD;
    float acc = 0.f;
#pragma unroll 8
    for (int k = 0; k < NEMBD; ++k)
        acc = fmaf(xr[k], W1[k * NHID + lane], acc);
    h1[(size_t)row * NHID + lane] = acc;
    float ts = wave_sum64(acc * a1s[lane]);
    float td = wave_sum64(acc * a1d[lane]);
    if (lane == 0) { als[row] = ts; ald[row] = td; }
}

// Layer-1 GAT: scan adj row -> neighbor list (ballot compaction, deterministic),
// save list to global for layer 2, sparse softmax, out = elu(sum p*h1 + b1).
// wave per row, lane = feature in accumulation phase.
__global__ __launch_bounds__(256) void k_gat1(
    const float* __restrict__ adj, const float* __restrict__ h1,
    const float* __restrict__ als, const float* __restrict__ ald,
    const float* __restrict__ b1, float* __restrict__ h1a,
    int* __restrict__ g_cnt, int* __restrict__ g_nbr) {
    __shared__ int   s_idx[4][MAXN];
    __shared__ float s_p[4][MAXN];
    int wid = threadIdx.x >> 6, lane = threadIdx.x & 63;
    int row = blockIdx.x * 4 + wid;
    const float4* arow = (const float4*)(adj + (size_t)row * NN);
    unsigned long long lt = (1ull << lane) - 1ull;

    // Phase 1: compact nonzero column indices (deterministic order, no atomics)
    int base = 0;
    for (int it = 0; it < NN / 256; ++it) {
        float4 v = arow[it * 64 + lane];
#pragma unroll
        for (int s = 0; s < 4; ++s) {
            float val = (s == 0) ? v.x : (s == 1) ? v.y : (s == 2) ? v.z : v.w;
            bool nz = val > 0.f;
            unsigned long long m = __ballot(nz);
            if (nz) {
                int pos = base + __popcll(m & lt);
                if (pos < MAXN) s_idx[wid][pos] = it * 256 + lane * 4 + s;
            }
            base += __popcll(m);
        }
    }
    int cnt = base < MAXN ? base : MAXN;
    if (lane == 0) g_cnt[row] = cnt;
    for (int n = lane; n < cnt; n += 64) g_nbr[(size_t)row * MAXN + n] = s_idx[wid][n];

    // Phase 2: e = leaky(as_i + ad_j), wave softmax over neighbor list
    float asrow = als[row];
    float mloc = -1e30f;
    for (int n = lane; n < cnt; n += 64) {
        int j = s_idx[wid][n];
        float e = asrow + ald[j];
        e = e > 0.f ? e : NEG_SLOPE * e;
        s_p[wid][n] = e;
        mloc = fmaxf(mloc, e);
    }
    float mrow = wave_max64(mloc);
    float ssum = 0.f;
    for (int n = lane; n < cnt; n += 64) {
        float p = __expf(s_p[wid][n] - mrow);
        s_p[wid][n] = p;
        ssum += p;
    }
    float rinv = 1.f / wave_sum64(ssum);

    // Phase 3: out[row][lane] = (sum_n p_n * h1[j_n][lane]) * rinv + b1, then ELU
    float acc = 0.f;
#pragma unroll 4
    for (int n = 0; n < cnt; ++n) {
        float p = s_p[wid][n];
        int j = s_idx[wid][n];
        acc = fmaf(p, h1[(size_t)j * NHID + lane], acc);
    }
    acc = acc * rinv + b1[lane];
    float o = acc > 0.f ? acc : expm1f(acc);
    h1a[(size_t)row * NHID + lane] = o;
}

// h2 = h1a @ W2 (64->16), alphas. wave per row, lane = c + 16*k
__global__ __launch_bounds__(256) void k_h2(
    const float* __restrict__ h1a, const float* __restrict__ W2,
    const float* __restrict__ a2s, const float* __restrict__ a2d,
    float* __restrict__ h2, float* __restrict__ als2, float* __restrict__ ald2) {
    int wid = threadIdx.x >> 6, lane = threadIdx.x & 63;
    int row = blockIdx.x * 4 + wid;
    int c = lane & 15, k = lane >> 4;
    float acc = 0.f;
#pragma unroll
    for (int f = k; f < NHID; f += 4)
        acc = fmaf(h1a[(size_t)row * NHID + f], W2[f * NCLS + c], acc);
    acc += __shfl_xor(acc, 16);
    acc += __shfl_xor(acc, 32);   // all lanes of same c now hold h2[row][c]
    if (lane < 16) h2[(size_t)row * NCLS + lane] = acc;
    float ts = acc * a2s[c];
    float td = acc * a2d[c];
    ts += __shfl_xor(ts, 1); td += __shfl_xor(td, 1);
    ts += __shfl_xor(ts, 2); td += __shfl_xor(td, 2);
    ts += __shfl_xor(ts, 4); td += __shfl_xor(td, 4);
    ts += __shfl_xor(ts, 8); td += __shfl_xor(td, 8);
    if (lane == 0) { als2[row] = ts; ald2[row] = td; }
}

// Layer-2 GAT from saved neighbor lists. wave per row; accumulation lane=(c+16k).
__global__ __launch_bounds__(256) void k_gat2(
    const float* __restrict__ h2, const float* __restrict__ als2,
    const float* __restrict__ ald2, const float* __restrict__ b2,
    const int* __restrict__ g_cnt, const int* __restrict__ g_nbr,
    float* __restrict__ out) {
    __shared__ int   s_idx[4][MAXN];
    __shared__ float s_p[4][MAXN];
    int wid = threadIdx.x >> 6, lane = threadIdx.x & 63;
    int row = blockIdx.x * 4 + wid;
    int cnt = g_cnt[row];
    for (int n = lane; n < cnt; n += 64) s_idx[wid][n] = g_nbr[(size_t)row * MAXN + n];

    float asrow = als2[row];
    float mloc = -1e30f;
    for (int n = lane; n < cnt; n += 64) {
        float e = asrow + ald2[s_idx[wid][n]];
        e = e > 0.f ? e : NEG_SLOPE * e;
        s_p[wid][n] = e;
        mloc = fmaxf(mloc, e);
    }
    float mrow = wave_max64(mloc);
    float ssum = 0.f;
    for (int n = lane; n < cnt; n += 64) {
        float p = __expf(s_p[wid][n] - mrow);
        s_p[wid][n] = p;
        ssum += p;
    }
    float rinv = 1.f / wave_sum64(ssum);

    int c = lane & 15, k = lane >> 4;
    float acc = 0.f;
    for (int n = k; n < cnt; n += 4)
        acc = fmaf(s_p[wid][n], h2[(size_t)s_idx[wid][n] * NCLS + c], acc);
    acc += __shfl_xor(acc, 16);
    acc += __shfl_xor(acc, 32);
    if (k == 0) {
        float o = acc * rinv + b2[c];
        o = o > 0.f ? o : expm1f(o);
        out[(size_t)row * NCLS + c] = o;
    }
}

extern "C" void kernel_launch(void* const* d_in, const int* in_sizes, int n_in,
                              void* d_out, int out_size, void* d_ws, size_t ws_size,
                              hipStream_t stream) {
    const float* x   = (const float*)d_in[0];
    const float* adj = (const float*)d_in[1];
    const float* W1  = (const float*)d_in[2];
    const float* a1s = (const float*)d_in[3];
    const float* a1d = (const float*)d_in[4];
    const float* b1  = (const float*)d_in[5];
    const float* W2  = (const float*)d_in[6];
    const float* a2s = (const float*)d_in[7];
    const float* a2d = (const float*)d_in[8];
    const float* b2  = (const float*)d_in[9];
    float* out = (float*)d_out;

    char* ws = (char*)d_ws;
    float* h1   = (float*)(ws + 0);          // 8192*64*4  = 2,097,152
    float* h1a  = (float*)(ws + 2097152);    // 2,097,152
    float* h2v  = (float*)(ws + 4194304);    // 8192*16*4  = 524,288
    float* als1 = (float*)(ws + 4718592);    // 32,768
    float* ald1 = (float*)(ws + 4751360);    // 32,768
    float* als2 = (float*)(ws + 4784128);    // 32,768
    float* ald2 = (float*)(ws + 4816896);    // 32,768
    int*   gcnt = (int*)  (ws + 4849664);    // 32,768
    int*   gnbr = (int*)  (ws + 4882432);    // 8192*256*4 = 8,388,608 -> total ~12.7 MB

    dim3 blk(256);
    dim3 grid(NN / 4);
    k_h1  <<<grid, blk, 0, stream>>>(x, W1, a1s, a1d, h1, als1, ald1);
    k_gat1<<<grid, blk, 0, stream>>>(adj, h1, als1, ald1, b1, h1a, gcnt, gnbr);
    k_h2  <<<grid, blk, 0, stream>>>(h1a, W2, a2s, a2d, h2v, als2, ald2);
    k_gat2<<<grid, blk, 0, stream>>>(h2v, als2, ald2, b2, gcnt, gnbr, out);
}

// Round 2
// 88.202 us; speedup vs baseline: 1.0751x; 1.0751x over previous
//
#include <hip/hip_runtime.h>
#include <math.h>

#define NN 8192
#define NEMBD 128
#define NHID 64
#define NCLS 16
#define MAXN 256
#define NEG_SLOPE 0.2f

typedef float f4 __attribute__((ext_vector_type(4)));

__device__ __forceinline__ float wave_max64(float v) {
    v = fmaxf(v, __shfl_xor(v, 1));
    v = fmaxf(v, __shfl_xor(v, 2));
    v = fmaxf(v, __shfl_xor(v, 4));
    v = fmaxf(v, __shfl_xor(v, 8));
    v = fmaxf(v, __shfl_xor(v, 16));
    v = fmaxf(v, __shfl_xor(v, 32));
    return v;
}
__device__ __forceinline__ float wave_sum64(float v) {
    v += __shfl_xor(v, 1);
    v += __shfl_xor(v, 2);
    v += __shfl_xor(v, 4);
    v += __shfl_xor(v, 8);
    v += __shfl_xor(v, 16);
    v += __shfl_xor(v, 32);
    return v;
}

// ---- K1 pieces -------------------------------------------------------------

__device__ __forceinline__ void compute_h1(
    int row, int lane,
    const float* __restrict__ x, const float* __restrict__ W1,
    const float* __restrict__ a1s, const float* __restrict__ a1d,
    float* __restrict__ h1, float* __restrict__ als, float* __restrict__ ald) {
    const float* xr = x + (size_t)row * NEMBD;
    float acc = 0.f;
#pragma unroll 8
    for (int k = 0; k < NEMBD; ++k)
        acc = fmaf(xr[k], W1[k * NHID + lane], acc);
    h1[(size_t)row * NHID + lane] = acc;
    float ts = wave_sum64(acc * a1s[lane]);
    float td = wave_sum64(acc * a1d[lane]);
    if (lane == 0) { als[row] = ts; ald[row] = td; }
}

__device__ __forceinline__ void scan_adj(
    int row, int lane, int* s_idx,
    const float* __restrict__ adj,
    int* __restrict__ g_cnt, int* __restrict__ g_nbr) {
    const f4* arow = (const f4*)(adj + (size_t)row * NN);
    unsigned long long lt = (1ull << lane) - 1ull;
    int base = 0;
    for (int it = 0; it < NN / 256; ++it) {
        f4 v = __builtin_nontemporal_load(arow + it * 64 + lane);
#pragma unroll
        for (int s = 0; s < 4; ++s) {
            bool nz = v[s] > 0.f;
            unsigned long long m = __ballot(nz);
            if (nz) {
                int pos = base + __popcll(m & lt);
                if (pos < MAXN) s_idx[pos] = it * 256 + lane * 4 + s;
            }
            base += __popcll(m);
        }
    }
    int cnt = base < MAXN ? base : MAXN;
    if (lane == 0) g_cnt[row] = cnt;
    for (int n = lane; n < cnt; n += 64)
        g_nbr[(size_t)row * MAXN + n] = s_idx[n];
}

// K1: fused h1 = x@W1 (+alphas) and adjacency-row scan -> neighbor lists.
// Even blocks: h1 then scan; odd blocks: scan then h1 (saturate HBM from t=0).
__global__ __launch_bounds__(256) void k1_h1_scan(
    const float* __restrict__ x, const float* __restrict__ W1,
    const float* __restrict__ a1s, const float* __restrict__ a1d,
    const float* __restrict__ adj,
    float* __restrict__ h1, float* __restrict__ als, float* __restrict__ ald,
    int* __restrict__ g_cnt, int* __restrict__ g_nbr) {
    __shared__ int s_idx[4][MAXN];
    int wid = threadIdx.x >> 6, lane = threadIdx.x & 63;
    int row = blockIdx.x * 4 + wid;
    if (blockIdx.x & 1) {
        scan_adj(row, lane, s_idx[wid], adj, g_cnt, g_nbr);
        compute_h1(row, lane, x, W1, a1s, a1d, h1, als, ald);
    } else {
        compute_h1(row, lane, x, W1, a1s, a1d, h1, als, ald);
        scan_adj(row, lane, s_idx[wid], adj, g_cnt, g_nbr);
    }
}

// K2: attn-1 softmax + gather + ELU (h1a stays in registers/LDS), then
// h2 = h1a @ W2 and layer-2 alphas. wave per row.
__global__ __launch_bounds__(256) void k2_attn1_h2(
    const float* __restrict__ h1, const float* __restrict__ als,
    const float* __restrict__ ald, const float* __restrict__ b1,
    const float* __restrict__ W2, const float* __restrict__ a2s,
    const float* __restrict__ a2d,
    const int* __restrict__ g_cnt, const int* __restrict__ g_nbr,
    float* __restrict__ h2, float* __restrict__ als2, float* __restrict__ ald2) {
    __shared__ int   s_idx[4][MAXN];
    __shared__ float s_p[4][MAXN];
    __shared__ float s_h[4][NHID];
    int wid = threadIdx.x >> 6, lane = threadIdx.x & 63;
    int row = blockIdx.x * 4 + wid;
    int cnt = g_cnt[row];
    for (int n = lane; n < cnt; n += 64) s_idx[wid][n] = g_nbr[(size_t)row * MAXN + n];

    float asrow = als[row];
    float mloc = -1e30f;
    for (int n = lane; n < cnt; n += 64) {
        float e = asrow + ald[s_idx[wid][n]];
        e = e > 0.f ? e : NEG_SLOPE * e;
        s_p[wid][n] = e;
        mloc = fmaxf(mloc, e);
    }
    float mrow = wave_max64(mloc);
    float ssum = 0.f;
    for (int n = lane; n < cnt; n += 64) {
        float p = __expf(s_p[wid][n] - mrow);
        s_p[wid][n] = p;
        ssum += p;
    }
    float rinv = 1.f / wave_sum64(ssum);

    float acc = 0.f;
#pragma unroll 4
    for (int n = 0; n < cnt; ++n)
        acc = fmaf(s_p[wid][n], h1[(size_t)s_idx[wid][n] * NHID + lane], acc);
    acc = acc * rinv + b1[lane];
    float o = acc > 0.f ? acc : expm1f(acc);
    s_h[wid][lane] = o;

    // h2[row][c] = sum_f s_h[f] * W2[f][c]; lane = (c, k) with f-chunk per k
    int c = lane & 15, k = lane >> 4;
    float a2 = 0.f;
#pragma unroll
    for (int f = k * 16; f < k * 16 + 16; ++f)
        a2 = fmaf(s_h[wid][f], W2[f * NCLS + c], a2);
    a2 += __shfl_xor(a2, 16);
    a2 += __shfl_xor(a2, 32);   // all lanes with same c hold h2[row][c]
    if (lane < 16) h2[(size_t)row * NCLS + lane] = a2;
    float ts = a2 * a2s[c], td = a2 * a2d[c];
    ts += __shfl_xor(ts, 1); td += __shfl_xor(td, 1);
    ts += __shfl_xor(ts, 2); td += __shfl_xor(td, 2);
    ts += __shfl_xor(ts, 4); td += __shfl_xor(td, 4);
    ts += __shfl_xor(ts, 8); td += __shfl_xor(td, 8);
    if (lane == 0) { als2[row] = ts; ald2[row] = td; }
}

// K3: layer-2 GAT from saved neighbor lists. wave per row; lane = (c, k).
__global__ __launch_bounds__(256) void k3_attn2(
    const float* __restrict__ h2, const float* __restrict__ als2,
    const float* __restrict__ ald2, const float* __restrict__ b2,
    const int* __restrict__ g_cnt, const int* __restrict__ g_nbr,
    float* __restrict__ out) {
    __shared__ int   s_idx[4][MAXN];
    __shared__ float s_p[4][MAXN];
    int wid = threadIdx.x >> 6, lane = threadIdx.x & 63;
    int row = blockIdx.x * 4 + wid;
    int cnt = g_cnt[row];
    for (int n = lane; n < cnt; n += 64) s_idx[wid][n] = g_nbr[(size_t)row * MAXN + n];

    float asrow = als2[row];
    float mloc = -1e30f;
    for (int n = lane; n < cnt; n += 64) {
        float e = asrow + ald2[s_idx[wid][n]];
        e = e > 0.f ? e : NEG_SLOPE * e;
        s_p[wid][n] = e;
        mloc = fmaxf(mloc, e);
    }
    float mrow = wave_max64(mloc);
    float ssum = 0.f;
    for (int n = lane; n < cnt; n += 64) {
        float p = __expf(s_p[wid][n] - mrow);
        s_p[wid][n] = p;
        ssum += p;
    }
    float rinv = 1.f / wave_sum64(ssum);

    int c = lane & 15, k = lane >> 4;
    float acc = 0.f;
    for (int n = k; n < cnt; n += 4)
        acc = fmaf(s_p[wid][n], h2[(size_t)s_idx[wid][n] * NCLS + c], acc);
    acc += __shfl_xor(acc, 16);
    acc += __shfl_xor(acc, 32);
    if (k == 0) {
        float o = acc * rinv + b2[c];
        o = o > 0.f ? o : expm1f(o);
        out[(size_t)row * NCLS + c] = o;
    }
}

extern "C" void kernel_launch(void* const* d_in, const int* in_sizes, int n_in,
                              void* d_out, int out_size, void* d_ws, size_t ws_size,
                              hipStream_t stream) {
    const float* x   = (const float*)d_in[0];
    const float* adj = (const float*)d_in[1];
    const float* W1  = (const float*)d_in[2];
    const float* a1s = (const float*)d_in[3];
    const float* a1d = (const float*)d_in[4];
    const float* b1  = (const float*)d_in[5];
    const float* W2  = (const float*)d_in[6];
    const float* a2s = (const float*)d_in[7];
    const float* a2d = (const float*)d_in[8];
    const float* b2  = (const float*)d_in[9];
    float* out = (float*)d_out;

    char* ws = (char*)d_ws;
    float* h1   = (float*)(ws + 0);          // 8192*64*4  = 2,097,152
    float* h2v  = (float*)(ws + 2097152);    // 8192*16*4  = 524,288
    float* als1 = (float*)(ws + 2621440);    // 32,768
    float* ald1 = (float*)(ws + 2654208);    // 32,768
    float* als2 = (float*)(ws + 2686976);    // 32,768
    float* ald2 = (float*)(ws + 2719744);    // 32,768
    int*   gcnt = (int*)  (ws + 2752512);    // 32,768
    int*   gnbr = (int*)  (ws + 2785280);    // 8192*256*4 = 8,388,608 -> ~11.2 MB total

    dim3 blk(256);
    dim3 grid(NN / 4);
    k1_h1_scan<<<grid, blk, 0, stream>>>(x, W1, a1s, a1d, adj, h1, als1, ald1, gcnt, gnbr);
    k2_attn1_h2<<<grid, blk, 0, stream>>>(h1, als1, ald1, b1, W2, a2s, a2d, gcnt, gnbr,
                                          h2v, als2, ald2);
    k3_attn2<<<grid, blk, 0, stream>>>(h2v, als2, ald2, b2, gcnt, gnbr, out);
}